// Round 4
// baseline (209.113 us; speedup 1.0000x reference)
//
#include <hip/hip_runtime.h>
#include <math.h>

#define Bn 32
#define Ln 524288
#define NF 4

#define TPB  256
#define CHK  32
#define TILE (TPB * CHK)        // 8192 samples
#define TPR  (Ln / TILE)        // 64 tiles per row
#define NT   (Bn * TPR)         // 2048 tiles
#define LOOKB 16                // truncated lookback depth (K^16 ~ 1e-57)

// ---- ws layout (float indices) ----
#define COEF_OFF 0               // 20 floats
#define POWJ_OFF 64              // j=0..5: A^(32*2^j)            (384)
#define XW_OFF   448             // m=0..3: A^(2048m), m0=I        (256)
#define LBK_OFF  704             // m=0..15: K^m, K=A^8192, m0=I  (1024)
#define AGG_OFF  1728            // NT*8 tile aggregates
#define FLAG_I   (AGG_OFF + NT * 8)  // int idx: NT flags
#define CNT_I    (FLAG_I + NT)       // 1 int

// ---- LDS layout (float indices) ----
#define MATS_L 8192              // copy of ws[64..1728)
#define POWJ_L (MATS_L + 0)
#define XW_L   (MATS_L + 384)
#define LBK_L  (MATS_L + 640)
#define WAGG_L (MATS_L + 1664)   // 4 waves * 8
#define E_L    (WAGG_L + 32)     // 8
#define TID_L  (E_L + 8)         // 1 int
#define LDS_F  (TID_L + 8)

// ---------------------------------------------------------------------------
__global__ void precompute_k(const float* __restrict__ lr,
                             const float* __restrict__ ra,
                             const float* __restrict__ b0,
                             const float* __restrict__ b1,
                             const float* __restrict__ b2,
                             float* __restrict__ ws) {
    __shared__ double Md[64], Td[64], X2d[64], X4d[64], Pd[64];
    const int t = threadIdx.x;  // 64 threads

    int* fl = (int*)ws;
    for (int i = t; i < NT; i += 64) fl[FLAG_I + i] = 0;
    if (t == 0) fl[CNT_I] = 0;

    if (t < NF) {
        double r   = 0.999 / (1.0 + exp(-(double)lr[t]));
        double ang = 3.14159265358979323846 / (1.0 + exp(-(double)ra[t]));
        ws[COEF_OFF + t * 5 + 0] = b0[t];
        ws[COEF_OFF + t * 5 + 1] = b1[t];
        ws[COEF_OFF + t * 5 + 2] = b2[t];
        ws[COEF_OFF + t * 5 + 3] = (float)(-2.0 * r * cos(ang));
        ws[COEF_OFF + t * 5 + 4] = (float)(r * r);
    }
    __syncthreads();

    if (t < 8) {  // A^CHK via unit-state simulation (f32-rounded coefs)
        double cb0[NF], cb1[NF], cb2[NF], ca1[NF], ca2[NF];
        for (int f = 0; f < NF; ++f) {
            cb0[f] = (double)ws[COEF_OFF + f * 5 + 0];
            cb1[f] = (double)ws[COEF_OFF + f * 5 + 1];
            cb2[f] = (double)ws[COEF_OFF + f * 5 + 2];
            ca1[f] = (double)ws[COEF_OFF + f * 5 + 3];
            ca2[f] = (double)ws[COEF_OFF + f * 5 + 4];
        }
        double s[8];
        for (int r = 0; r < 8; ++r) s[r] = 0.0;
        s[t] = 1.0;
        for (int n = 0; n < CHK; ++n) {
            double v = 0.0;
            for (int f = 0; f < NF; ++f) {
                double y     = cb0[f] * v + s[2 * f];
                s[2 * f]     = cb1[f] * v - ca1[f] * y + s[2 * f + 1];
                s[2 * f + 1] = cb2[f] * v - ca2[f] * y;
                v = y;
            }
        }
        for (int r = 0; r < 8; ++r) Md[r * 8 + t] = s[r];  // column t of A^32
    }
    __syncthreads();

    ws[POWJ_OFF + t] = (float)Md[t];  // j=0
    const int r8 = t >> 3, c8 = t & 7;
    for (int sq = 1; sq <= 8; ++sq) {  // -> A^(32*2^sq)
        double acc = 0.0;
        for (int m = 0; m < 8; ++m) acc += Md[r8 * 8 + m] * Md[m * 8 + c8];
        Td[t] = acc;
        __syncthreads();
        Md[t] = Td[t];
        __syncthreads();
        if (sq <= 5) ws[POWJ_OFF + sq * 64 + t] = (float)Md[t];
        if (sq == 6) { X2d[t] = Md[t]; ws[XW_OFF + 64 + t]  = (float)Md[t]; }  // A^2048
        if (sq == 7) { X4d[t] = Md[t]; ws[XW_OFF + 128 + t] = (float)Md[t]; }  // A^4096
    }
    // Md = K = A^8192
    ws[XW_OFF + t]  = (r8 == c8) ? 1.f : 0.f;   // XW[0] = I
    ws[LBK_OFF + t] = (r8 == c8) ? 1.f : 0.f;   // K^0 = I
    {   // XW[3] = A^6144 = A^2048 * A^4096
        double acc = 0.0;
        for (int m = 0; m < 8; ++m) acc += X2d[r8 * 8 + m] * X4d[m * 8 + c8];
        ws[XW_OFF + 192 + t] = (float)acc;
    }
    Pd[t] = Md[t];
    ws[LBK_OFF + 64 + t] = (float)Pd[t];        // K^1
    __syncthreads();
    for (int m = 2; m < LOOKB; ++m) {
        double acc = 0.0;
        for (int j = 0; j < 8; ++j) acc += Pd[r8 * 8 + j] * Md[j * 8 + c8];
        Td[t] = acc;
        __syncthreads();
        Pd[t] = Td[t];
        __syncthreads();
        ws[LBK_OFF + m * 64 + t] = (float)Pd[t];
    }
}

// ---------------------------------------------------------------------------
__device__ __forceinline__ void step1(float& u, float* s,
                                      const float* c0, const float* c1,
                                      const float* c2, const float* A1,
                                      const float* A2) {
#pragma unroll
    for (int f = 0; f < NF; ++f) {
        float yv     = fmaf(c0[f], u, s[2 * f]);
        s[2 * f]     = fmaf(-A1[f], yv, fmaf(c1[f], u, s[2 * f + 1]));
        s[2 * f + 1] = fmaf(-A2[f], yv, c2[f] * u);
        u = yv;
    }
}

// o += T(8x8, LDS row-major) * p
__device__ __forceinline__ void matvec_acc(float* o, const float* T, const float* p) {
#pragma unroll
    for (int r = 0; r < 8; ++r) {
        const float4 t0 = *(const float4*)(T + r * 8);
        const float4 t1 = *(const float4*)(T + r * 8 + 4);
        o[r] = fmaf(t0.x, p[0], fmaf(t0.y, p[1], fmaf(t0.z, p[2], fmaf(t0.w, p[3],
               fmaf(t1.x, p[4], fmaf(t1.y, p[5], fmaf(t1.z, p[6], fmaf(t1.w, p[7], o[r]))))))));
    }
}
// h = T * h
__device__ __forceinline__ void matvec_rep(float* h, const float* T) {
    float tmp[8];
#pragma unroll
    for (int r = 0; r < 8; ++r) {
        const float4 t0 = *(const float4*)(T + r * 8);
        const float4 t1 = *(const float4*)(T + r * 8 + 4);
        tmp[r] = fmaf(t0.x, h[0], fmaf(t0.y, h[1], fmaf(t0.z, h[2], fmaf(t0.w, h[3],
                 fmaf(t1.x, h[4], fmaf(t1.y, h[5], fmaf(t1.z, h[6], t1.w * h[7])))))));
    }
#pragma unroll
    for (int r = 0; r < 8; ++r) h[r] = tmp[r];
}

// ---------------------------------------------------------------------------
// Single-pass scan: one WG = 8192-sample tile, 256 thr x 32 samples.
// ---------------------------------------------------------------------------
__global__ __launch_bounds__(TPB, 4) void biquad_sp_k(const float* __restrict__ x,
                                                      float* __restrict__ ws,
                                                      float* __restrict__ y) {
    __shared__ __align__(16) float ldsf[LDS_F];
    float4* lds4 = (float4*)ldsf;
    const int t    = threadIdx.x;
    const int lane = t & 63;
    const int w    = t >> 6;
    int* flags = (int*)ws + FLAG_I;

    if (t == 0) *(int*)&ldsf[TID_L] = atomicAdd((int*)ws + CNT_I, 1);
    __syncthreads();
    const int tile = *(const int*)&ldsf[TID_L];
    const int row  = tile / TPR;
    const int tpos = tile % TPR;

    // stage x -> LDS (coalesced reads, XOR-swizzled slots); matrices -> LDS
    const float4* xg = (const float4*)x + (size_t)row * (Ln / 4) + (size_t)tpos * (TILE / 4);
#pragma unroll
    for (int j = 0; j < TILE / 4 / TPB; ++j) {  // 8
        const int n    = j * TPB + t;
        const int slot = (n & ~7) | ((n & 7) ^ ((n >> 3) & 7));
        lds4[slot] = xg[n];
    }
    for (int i = t; i < 1664; i += TPB) ldsf[MATS_L + i] = ws[POWJ_OFF + i];

    float c0[NF], c1[NF], c2[NF], A1[NF], A2[NF];
#pragma unroll
    for (int f = 0; f < NF; ++f) {
        c0[f] = ws[COEF_OFF + f * 5 + 0];
        c1[f] = ws[COEF_OFF + f * 5 + 1];
        c2[f] = ws[COEF_OFF + f * 5 + 2];
        A1[f] = ws[COEF_OFF + f * 5 + 3];
        A2[f] = ws[COEF_OFF + f * 5 + 4];
    }
    __syncthreads();

    // LDS -> regs (swizzle => conflict-free)
    float4 xr[CHK / 4];
#pragma unroll
    for (int i = 0; i < CHK / 4; ++i) xr[i] = lds4[t * 8 + (i ^ (t & 7))];

    // zero-state pass: chunk-final state d_t
    float s[8];
#pragma unroll
    for (int r = 0; r < 8; ++r) s[r] = 0.f;
#pragma unroll
    for (int i = 0; i < CHK / 4; ++i) {
        float q[4] = {xr[i].x, xr[i].y, xr[i].z, xr[i].w};
#pragma unroll
        for (int e = 0; e < 4; ++e) { float u = q[e]; step1(u, s, c0, c1, c2, A1, A2); }
    }

    // intra-wave affine Kogge-Stone over 64 chunks (register-only)
    float v[8];
#pragma unroll
    for (int r = 0; r < 8; ++r) v[r] = s[r];
#pragma unroll
    for (int j = 0; j < 6; ++j) {
        const int st = 1 << j;
        float p[8];
#pragma unroll
        for (int r = 0; r < 8; ++r) p[r] = __shfl_up(v[r], st, 64);
        if (lane >= st) matvec_acc(v, ldsf + POWJ_L + j * 64, p);
    }

    // wave aggregates -> LDS
    if (lane == 63) {
#pragma unroll
        for (int r = 0; r < 8; ++r) ldsf[WAGG_L + w * 8 + r] = v[r];
    }
    __syncthreads();

    // prevAgg(w) = sum_{k<w} A^(2048k) * W_{w-1-k}
    float pa[8];
#pragma unroll
    for (int r = 0; r < 8; ++r) pa[r] = 0.f;
#pragma unroll
    for (int k = 0; k < 3; ++k) {
        if (k < w) {
            const float* Wk = ldsf + WAGG_L + (w - 1 - k) * 8;
            if (k == 0) {
#pragma unroll
                for (int r = 0; r < 8; ++r) pa[r] += Wk[r];
            } else {
                matvec_acc(pa, ldsf + XW_L + k * 64, Wk);
            }
        }
    }

    // publish tile aggregate D = v_255 + A^2048 * prevAgg(3)
    if (t == TPB - 1) {
        float D[8];
#pragma unroll
        for (int r = 0; r < 8; ++r) D[r] = v[r];
        matvec_acc(D, ldsf + XW_L + 64, pa);
        float* ag = ws + AGG_OFF + (size_t)tile * 8;
#pragma unroll
        for (int r = 0; r < 8; ++r) ag[r] = D[r];
        __threadfence();
        __hip_atomic_store(&flags[tile], 1, __ATOMIC_RELEASE, __HIP_MEMORY_SCOPE_AGENT);
    }

    // truncated lookback (wave 0): E = sum_{m<min(tpos,16)} K^m * D[tile-1-m]
    if (w == 0) {
        float e8[8];
#pragma unroll
        for (int r = 0; r < 8; ++r) e8[r] = 0.f;
        if (lane < LOOKB && lane < tpos) {
            const int pt = tile - 1 - lane;
            if (__hip_atomic_load(&flags[pt], __ATOMIC_ACQUIRE,
                                  __HIP_MEMORY_SCOPE_AGENT) == 0) {
                do { __builtin_amdgcn_s_sleep(2); }
                while (__hip_atomic_load(&flags[pt], __ATOMIC_ACQUIRE,
                                         __HIP_MEMORY_SCOPE_AGENT) == 0);
            }
            const float4* Dp = (const float4*)(ws + AGG_OFF + (size_t)pt * 8);
            const float4 da = Dp[0], db = Dp[1];
            const float dv[8] = {da.x, da.y, da.z, da.w, db.x, db.y, db.z, db.w};
            matvec_acc(e8, ldsf + LBK_L + lane * 64, dv);
        }
#pragma unroll
        for (int off = 8; off >= 1; off >>= 1) {
#pragma unroll
            for (int r = 0; r < 8; ++r) e8[r] += __shfl_xor(e8[r], off, 64);
        }
        if (lane == 0) {
#pragma unroll
            for (int r = 0; r < 8; ++r) ldsf[E_L + r] = e8[r];
        }
    }
    __syncthreads();

    // H = prevAgg(w) + A^(2048w)*E ; entry(t) = A^(32*lane)*H + v_{lane-1}
    float E[8];
#pragma unroll
    for (int r = 0; r < 8; ++r) E[r] = ldsf[E_L + r];
    float H[8];
#pragma unroll
    for (int r = 0; r < 8; ++r) H[r] = pa[r];
    matvec_acc(H, ldsf + XW_L + w * 64, E);  // XW[0]=I
#pragma unroll
    for (int j = 0; j < 6; ++j) {
        if (lane & (1 << j)) matvec_rep(H, ldsf + POWJ_L + j * 64);
    }
    float pv[8];
#pragma unroll
    for (int r = 0; r < 8; ++r) pv[r] = __shfl_up(v[r], 1, 64);
#pragma unroll
    for (int r = 0; r < 8; ++r) s[r] = H[r] + ((lane > 0) ? pv[r] : 0.f);

    // final pass from exact entry state, in place xr -> y values
#pragma unroll
    for (int i = 0; i < CHK / 4; ++i) {
        float q[4] = {xr[i].x, xr[i].y, xr[i].z, xr[i].w};
#pragma unroll
        for (int e = 0; e < 4; ++e) { float u = q[e]; step1(u, s, c0, c1, c2, A1, A2); q[e] = u; }
        xr[i].x = q[0]; xr[i].y = q[1]; xr[i].z = q[2]; xr[i].w = q[3];
    }

    // y regs -> LDS (own slots, swizzled) -> global coalesced
#pragma unroll
    for (int i = 0; i < CHK / 4; ++i) lds4[t * 8 + (i ^ (t & 7))] = xr[i];
    __syncthreads();

    float4* yg = (float4*)y + (size_t)row * (Ln / 4) + (size_t)tpos * (TILE / 4);
#pragma unroll
    for (int j = 0; j < TILE / 4 / TPB; ++j) {
        const int n    = j * TPB + t;
        const int slot = (n & ~7) | ((n & 7) ^ ((n >> 3) & 7));
        yg[n] = lds4[slot];
    }
}

// ---------------------------------------------------------------------------
extern "C" void kernel_launch(void* const* d_in, const int* in_sizes, int n_in,
                              void* d_out, int out_size, void* d_ws, size_t ws_size,
                              hipStream_t stream) {
    const float* x  = (const float*)d_in[0];
    const float* lr = (const float*)d_in[1];
    const float* ra = (const float*)d_in[2];
    const float* b0 = (const float*)d_in[3];
    const float* b1 = (const float*)d_in[4];
    const float* b2 = (const float*)d_in[5];
    float* y  = (float*)d_out;
    float* ws = (float*)d_ws;

    precompute_k<<<dim3(1), dim3(64), 0, stream>>>(lr, ra, b0, b1, b2, ws);
    biquad_sp_k<<<dim3(NT), dim3(TPB), 0, stream>>>(x, ws, y);
}

// Round 6
// 76.691 us; speedup vs baseline: 2.7267x; 2.7267x over previous
//
#include <hip/hip_runtime.h>
#include <math.h>

#define Bn 32
#define Ln 524288
#define NF 4

#define TPB   512               // threads per WG (8 waves)
#define CPT   20                // samples per thread (5 float4)
#define S_WG  (TPB * CPT)       // 10240 samples staged per WG
#define OUT   8192              // output samples per WG
#define WU    (S_WG - OUT)      // 2048 warm-up samples
#define SLOT  (S_WG / 4)        // 2560 float4 slots
#define OSLOT (OUT / 4)         // 2048
#define WSLOT (WU / 4)          // 512
#define TPR   (Ln / OUT)        // 64 tiles per row
#define NT    (Bn * TPR)        // 2048 WGs

// ws layout (float indices): no flags, no aggregates — nothing inter-WG.
#define COEF_OFF 0               // 20 floats
#define POWJ_OFF 64              // j=0..5: A^(20*2^j)  (384 floats)
#define XW1_OFF  448             // A^1280 (wave span)   (64 floats)

// LDS layout (float indices)
#define X_L    0                 // padded float4 slots: 2880*4 = 11520 floats
#define MAT_L  11520             // POWJ 384 + XW1 64 = 448
#define WAGG_L 11968             // 8 waves * 8
#define PA_L   12032             // 8 waves * 8
#define LDS_F  12096             // 48384 bytes -> 3 WG/CU

__device__ __forceinline__ int pad4(int q) { return q + (q >> 3); }

// ---------------------------------------------------------------------------
// Precompute (1 block, 64 thr): f32-rounded coefs; A^20 via unit-state sim
// (double); squaring chain A^(20*2^j) j=0..5 and XW1 = A^1280.
// ---------------------------------------------------------------------------
__global__ void precompute_k(const float* __restrict__ lr,
                             const float* __restrict__ ra,
                             const float* __restrict__ b0,
                             const float* __restrict__ b1,
                             const float* __restrict__ b2,
                             float* __restrict__ ws) {
    __shared__ double Md[64], Td[64];
    const int t = threadIdx.x;

    if (t < NF) {
        double r   = 0.999 / (1.0 + exp(-(double)lr[t]));
        double ang = 3.14159265358979323846 / (1.0 + exp(-(double)ra[t]));
        ws[COEF_OFF + t * 5 + 0] = b0[t];
        ws[COEF_OFF + t * 5 + 1] = b1[t];
        ws[COEF_OFF + t * 5 + 2] = b2[t];
        ws[COEF_OFF + t * 5 + 3] = (float)(-2.0 * r * cos(ang));
        ws[COEF_OFF + t * 5 + 4] = (float)(r * r);
    }
    __syncthreads();

    if (t < 8) {
        double cb0[NF], cb1[NF], cb2[NF], ca1[NF], ca2[NF];
        for (int f = 0; f < NF; ++f) {
            cb0[f] = (double)ws[COEF_OFF + f * 5 + 0];
            cb1[f] = (double)ws[COEF_OFF + f * 5 + 1];
            cb2[f] = (double)ws[COEF_OFF + f * 5 + 2];
            ca1[f] = (double)ws[COEF_OFF + f * 5 + 3];
            ca2[f] = (double)ws[COEF_OFF + f * 5 + 4];
        }
        double s[8];
        for (int r = 0; r < 8; ++r) s[r] = 0.0;
        s[t] = 1.0;
        for (int n = 0; n < CPT; ++n) {
            double v = 0.0;
            for (int f = 0; f < NF; ++f) {
                double y     = cb0[f] * v + s[2 * f];
                s[2 * f]     = cb1[f] * v - ca1[f] * y + s[2 * f + 1];
                s[2 * f + 1] = cb2[f] * v - ca2[f] * y;
                v = y;
            }
        }
        for (int r = 0; r < 8; ++r) Md[r * 8 + t] = s[r];  // column t of A^20
    }
    __syncthreads();

    ws[POWJ_OFF + t] = (float)Md[t];  // j=0: A^20
    const int r8 = t >> 3, c8 = t & 7;
    for (int sq = 1; sq <= 6; ++sq) {
        double acc = 0.0;
        for (int m = 0; m < 8; ++m) acc += Md[r8 * 8 + m] * Md[m * 8 + c8];
        Td[t] = acc;
        __syncthreads();
        Md[t] = Td[t];
        __syncthreads();
        if (sq <= 5) ws[POWJ_OFF + sq * 64 + t] = (float)Md[t];  // A^(20*2^sq)
        else         ws[XW1_OFF + t]            = (float)Md[t];  // A^1280
    }
}

// ---------------------------------------------------------------------------
__device__ __forceinline__ void step1(float& u, float* s,
                                      const float* c0, const float* c1,
                                      const float* c2, const float* A1,
                                      const float* A2) {
#pragma unroll
    for (int f = 0; f < NF; ++f) {
        float yv     = fmaf(c0[f], u, s[2 * f]);
        s[2 * f]     = fmaf(-A1[f], yv, fmaf(c1[f], u, s[2 * f + 1]));
        s[2 * f + 1] = fmaf(-A2[f], yv, c2[f] * u);
        u = yv;
    }
}

__device__ __forceinline__ void matvec_acc(float* o, const float* T, const float* p) {
#pragma unroll
    for (int r = 0; r < 8; ++r) {
        const float4 t0 = *(const float4*)(T + r * 8);
        const float4 t1 = *(const float4*)(T + r * 8 + 4);
        o[r] = fmaf(t0.x, p[0], fmaf(t0.y, p[1], fmaf(t0.z, p[2], fmaf(t0.w, p[3],
               fmaf(t1.x, p[4], fmaf(t1.y, p[5], fmaf(t1.z, p[6], fmaf(t1.w, p[7], o[r]))))))));
    }
}
__device__ __forceinline__ void matvec_rep(float* h, const float* T) {
    float tmp[8];
#pragma unroll
    for (int r = 0; r < 8; ++r) {
        const float4 t0 = *(const float4*)(T + r * 8);
        const float4 t1 = *(const float4*)(T + r * 8 + 4);
        tmp[r] = fmaf(t0.x, h[0], fmaf(t0.y, h[1], fmaf(t0.z, h[2], fmaf(t0.w, h[3],
                 fmaf(t1.x, h[4], fmaf(t1.y, h[5], fmaf(t1.z, h[6], t1.w * h[7])))))));
    }
#pragma unroll
    for (int r = 0; r < 8; ++r) h[r] = tmp[r];
}

// ---------------------------------------------------------------------------
// One WG = one 8192-sample output tile + 2048-sample warm-up prefix.
// No inter-WG communication of any kind.
// ---------------------------------------------------------------------------
__global__ __launch_bounds__(TPB, 6) void biquad_k(const float* __restrict__ x,
                                                   const float* __restrict__ ws,
                                                   float* __restrict__ y) {
    __shared__ __align__(16) float ldsf[LDS_F];
    float4* lds4 = (float4*)ldsf;
    const int t    = threadIdx.x;
    const int lane = t & 63;
    const int w    = t >> 6;

    const int tile = blockIdx.x;
    const int row  = tile / TPR;
    const int tpos = tile % TPR;

    // stage x -> LDS (coalesced; padded slots). Warm-up region of tile 0 = zeros.
    const long gbase = (long)row * (Ln / 4) + (long)tpos * OSLOT - WSLOT;
    const float4* xg4 = (const float4*)x;
#pragma unroll
    for (int j = 0; j < SLOT / TPB; ++j) {  // 5
        const int n = j * TPB + t;
        float4 v = make_float4(0.f, 0.f, 0.f, 0.f);
        if (tpos > 0 || n >= WSLOT) v = xg4[gbase + n];
        lds4[pad4(n)] = v;
    }
    // matrices -> LDS
    for (int i = t; i < 448; i += TPB) ldsf[MAT_L + i] = ws[POWJ_OFF + i];

    float c0[NF], c1[NF], c2[NF], A1[NF], A2[NF];
#pragma unroll
    for (int f = 0; f < NF; ++f) {
        c0[f] = ws[COEF_OFF + f * 5 + 0];
        c1[f] = ws[COEF_OFF + f * 5 + 1];
        c2[f] = ws[COEF_OFF + f * 5 + 2];
        A1[f] = ws[COEF_OFF + f * 5 + 3];
        A2[f] = ws[COEF_OFF + f * 5 + 4];
    }
    __syncthreads();

    // zero-state pass over own 20-sample chunk (read LDS, keep only state)
    float s[8];
#pragma unroll
    for (int r = 0; r < 8; ++r) s[r] = 0.f;
#pragma unroll
    for (int i = 0; i < CPT / 4; ++i) {
        const float4 v = lds4[pad4(t * (CPT / 4) + i)];
        float q[4] = {v.x, v.y, v.z, v.w};
#pragma unroll
        for (int e = 0; e < 4; ++e) { float u = q[e]; step1(u, s, c0, c1, c2, A1, A2); }
    }

    // intra-wave affine Kogge-Stone over 64 chunks (registers + shfl)
    float v8[8];
#pragma unroll
    for (int r = 0; r < 8; ++r) v8[r] = s[r];
#pragma unroll
    for (int j = 0; j < 6; ++j) {
        const int st = 1 << j;
        float p[8];
#pragma unroll
        for (int r = 0; r < 8; ++r) p[r] = __shfl_up(v8[r], st, 64);
        if (lane >= st) matvec_acc(v8, ldsf + MAT_L + j * 64, p);
    }

    // wave aggregates -> LDS
    if (lane == 63) {
#pragma unroll
        for (int r = 0; r < 8; ++r) ldsf[WAGG_L + w * 8 + r] = v8[r];
    }
    __syncthreads();

    // cross-wave prefix (oldest-first Horner with XW1 = A^1280):
    //   s_enter(w) = XW1*s_enter(w-1) + W_{w-1}   (most recent gets I)
    if (w == 0 && lane < 8) {
        float acc[8];
#pragma unroll
        for (int r = 0; r < 8; ++r) acc[r] = 0.f;
        for (int m = 0; m < lane; ++m) {
            matvec_rep(acc, ldsf + MAT_L + 384);  // acc = XW1 * acc
#pragma unroll
            for (int r = 0; r < 8; ++r) acc[r] += ldsf[WAGG_L + m * 8 + r];
        }
#pragma unroll
        for (int r = 0; r < 8; ++r) ldsf[PA_L + lane * 8 + r] = acc[r];
    }
    __syncthreads();

    // entry(t) = A^(20*lane) * H_w + v_{lane-1}
    float H[8];
#pragma unroll
    for (int r = 0; r < 8; ++r) H[r] = ldsf[PA_L + w * 8 + r];
#pragma unroll
    for (int j = 0; j < 6; ++j) {
        if (lane & (1 << j)) matvec_rep(H, ldsf + MAT_L + j * 64);
    }
    float pv[8];
#pragma unroll
    for (int r = 0; r < 8; ++r) pv[r] = __shfl_up(v8[r], 1, 64);
#pragma unroll
    for (int r = 0; r < 8; ++r) s[r] = H[r] + ((lane > 0) ? pv[r] : 0.f);

    // final pass from exact entry state; write y values back into own slots
#pragma unroll
    for (int i = 0; i < CPT / 4; ++i) {
        const int qa = pad4(t * (CPT / 4) + i);
        const float4 v = lds4[qa];
        float q[4] = {v.x, v.y, v.z, v.w};
#pragma unroll
        for (int e = 0; e < 4; ++e) { float u = q[e]; step1(u, s, c0, c1, c2, A1, A2); q[e] = u; }
        lds4[qa] = make_float4(q[0], q[1], q[2], q[3]);
    }
    __syncthreads();

    // coalesced write of the output region (slots >= WSLOT)
    float4* yg4 = (float4*)y;
    const long obase = (long)row * (Ln / 4) + (long)tpos * OSLOT;
#pragma unroll
    for (int j = 0; j < OSLOT / TPB; ++j) {  // 4
        const int n = WSLOT + j * TPB + t;
        yg4[obase + (n - WSLOT)] = lds4[pad4(n)];
    }
}

// ---------------------------------------------------------------------------
extern "C" void kernel_launch(void* const* d_in, const int* in_sizes, int n_in,
                              void* d_out, int out_size, void* d_ws, size_t ws_size,
                              hipStream_t stream) {
    const float* x  = (const float*)d_in[0];
    const float* lr = (const float*)d_in[1];
    const float* ra = (const float*)d_in[2];
    const float* b0 = (const float*)d_in[3];
    const float* b1 = (const float*)d_in[4];
    const float* b2 = (const float*)d_in[5];
    float* y  = (float*)d_out;
    float* ws = (float*)d_ws;

    precompute_k<<<dim3(1), dim3(64), 0, stream>>>(lr, ra, b0, b1, b2, ws);
    biquad_k<<<dim3(NT), dim3(TPB), 0, stream>>>(x, ws, y);
}

// Round 7
// 53.613 us; speedup vs baseline: 3.9004x; 1.4305x over previous
//
#include <hip/hip_runtime.h>
#include <math.h>

#define Bn 32
#define Ln 524288
#define NF 4

#define TPB   512               // threads per WG (8 waves)
#define CPT   36                // samples per thread (9 float4)
#define S_WG  (TPB * CPT)       // 18432 samples staged per WG
#define OUT   16384             // output samples per WG
#define WU    (S_WG - OUT)      // 2048 warm-up samples
#define SLOT  (S_WG / 4)        // 4608 float4 slots
#define OSLOT (OUT / 4)         // 4096
#define WSLOT (WU / 4)          // 512
#define TPR   (Ln / OUT)        // 32 tiles per row
#define NT    (Bn * TPR)        // 1024 WGs

// ws layout (float indices) — nothing inter-WG.
#define COEF_OFF 0               // 20 floats
#define POWJ_OFF 64              // j=0..5: A^(36*2^j)  (384 floats)
#define XW1_OFF  448             // A^2304 (wave span)  (64 floats)

// LDS layout (float indices)
#define WAGG_L (SLOT * 4)        // 8 waves * 8
#define PA_L   (WAGG_L + 64)     // 8 waves * 8
#define LDS_F  (PA_L + 64)       // 18560 floats = 72.5 KB -> 2 WG/CU

__device__ __forceinline__ int swz(int n) {
    return (n & ~7) | ((n & 7) ^ ((n >> 3) & 7));
}

// ---------------------------------------------------------------------------
// Precompute (1 block, 64 thr): f32-rounded coefs; A^36 via unit-state sim
// (double); squaring chain A^(36*2^j) j=0..5 and XW1 = A^2304.
// A and all its powers are block-lower-triangular (filter f's state depends
// only on filters <= f), so upper blocks are exact zeros.
// ---------------------------------------------------------------------------
__global__ void precompute_k(const float* __restrict__ lr,
                             const float* __restrict__ ra,
                             const float* __restrict__ b0,
                             const float* __restrict__ b1,
                             const float* __restrict__ b2,
                             float* __restrict__ ws) {
    __shared__ double Md[64], Td[64];
    const int t = threadIdx.x;

    if (t < NF) {
        double r   = 0.999 / (1.0 + exp(-(double)lr[t]));
        double ang = 3.14159265358979323846 / (1.0 + exp(-(double)ra[t]));
        ws[COEF_OFF + t * 5 + 0] = b0[t];
        ws[COEF_OFF + t * 5 + 1] = b1[t];
        ws[COEF_OFF + t * 5 + 2] = b2[t];
        ws[COEF_OFF + t * 5 + 3] = (float)(-2.0 * r * cos(ang));
        ws[COEF_OFF + t * 5 + 4] = (float)(r * r);
    }
    __syncthreads();

    if (t < 8) {
        double cb0[NF], cb1[NF], cb2[NF], ca1[NF], ca2[NF];
        for (int f = 0; f < NF; ++f) {
            cb0[f] = (double)ws[COEF_OFF + f * 5 + 0];
            cb1[f] = (double)ws[COEF_OFF + f * 5 + 1];
            cb2[f] = (double)ws[COEF_OFF + f * 5 + 2];
            ca1[f] = (double)ws[COEF_OFF + f * 5 + 3];
            ca2[f] = (double)ws[COEF_OFF + f * 5 + 4];
        }
        double s[8];
        for (int r = 0; r < 8; ++r) s[r] = 0.0;
        s[t] = 1.0;
        for (int n = 0; n < CPT; ++n) {
            double v = 0.0;
            for (int f = 0; f < NF; ++f) {
                double y     = cb0[f] * v + s[2 * f];
                s[2 * f]     = cb1[f] * v - ca1[f] * y + s[2 * f + 1];
                s[2 * f + 1] = cb2[f] * v - ca2[f] * y;
                v = y;
            }
        }
        for (int r = 0; r < 8; ++r) Md[r * 8 + t] = s[r];  // column t of A^36
    }
    __syncthreads();

    ws[POWJ_OFF + t] = (float)Md[t];  // j=0: A^36
    const int r8 = t >> 3, c8 = t & 7;
    for (int sq = 1; sq <= 6; ++sq) {
        double acc = 0.0;
        for (int m = 0; m < 8; ++m) acc += Md[r8 * 8 + m] * Md[m * 8 + c8];
        Td[t] = acc;
        __syncthreads();
        Md[t] = Td[t];
        __syncthreads();
        if (sq <= 5) ws[POWJ_OFF + sq * 64 + t] = (float)Md[t];  // A^(36*2^sq)
        else         ws[XW1_OFF + t]            = (float)Md[t];  // A^2304
    }
}

// ---------------------------------------------------------------------------
__device__ __forceinline__ void step1(float& u, float* s,
                                      const float* c0, const float* c1,
                                      const float* c2, const float* A1,
                                      const float* A2) {
#pragma unroll
    for (int f = 0; f < NF; ++f) {
        float yv     = fmaf(c0[f], u, s[2 * f]);
        s[2 * f]     = fmaf(-A1[f], yv, fmaf(c1[f], u, s[2 * f + 1]));
        s[2 * f + 1] = fmaf(-A2[f], yv, c2[f] * u);
        u = yv;
    }
}

// Sparse (block-lower-triangular) 8x8 matvec; T is wave-uniform (global ws)
// so elements load to SGPRs. Row r uses columns 0..(r|1): 40 fma total.
__device__ __forceinline__ void matvec_acc_sp(float* o, const float* __restrict__ T,
                                              const float* p) {
#pragma unroll
    for (int r = 0; r < 8; ++r) {
        const int ncol = (r | 1) + 1;
#pragma unroll
        for (int c = 0; c < 8; ++c)
            if (c < ncol) o[r] = fmaf(T[r * 8 + c], p[c], o[r]);
    }
}
__device__ __forceinline__ void matvec_rep_sp(float* h, const float* __restrict__ T) {
    float tmp[8];
#pragma unroll
    for (int r = 0; r < 8; ++r) {
        const int ncol = (r | 1) + 1;
        float acc = 0.f;
#pragma unroll
        for (int c = 0; c < 8; ++c)
            if (c < ncol) acc = fmaf(T[r * 8 + c], h[c], acc);
        tmp[r] = acc;
    }
#pragma unroll
    for (int r = 0; r < 8; ++r) h[r] = tmp[r];
}

// ---------------------------------------------------------------------------
// One WG = one 16384-sample output tile + 2048-sample warm-up prefix.
// No inter-WG communication. x held in VGPRs between the two passes.
// ---------------------------------------------------------------------------
__global__ __launch_bounds__(TPB, 4) void biquad_k(const float* __restrict__ x,
                                                   const float* __restrict__ ws,
                                                   float* __restrict__ y) {
    __shared__ __align__(16) float ldsf[LDS_F];
    float4* lds4 = (float4*)ldsf;
    const int t    = threadIdx.x;
    const int lane = t & 63;
    const int w    = t >> 6;

    const int tile = blockIdx.x;
    const int row  = tile / TPR;
    const int tpos = tile % TPR;

    const float* __restrict__ mats = ws + POWJ_OFF;  // wave-uniform -> SGPR
    const float* __restrict__ xw1  = ws + XW1_OFF;

    // stage x -> LDS (coalesced; XOR-swizzled slots). Tile-0 warm-up = zeros.
    const long gbase = (long)row * (Ln / 4) + (long)tpos * OSLOT - WSLOT;
    const float4* xg4 = (const float4*)x;
#pragma unroll
    for (int j = 0; j < SLOT / TPB; ++j) {  // 9
        const int n = j * TPB + t;
        float4 v = make_float4(0.f, 0.f, 0.f, 0.f);
        if (tpos > 0 || n >= WSLOT) v = xg4[gbase + n];
        lds4[swz(n)] = v;
    }

    float c0[NF], c1[NF], c2[NF], A1[NF], A2[NF];
#pragma unroll
    for (int f = 0; f < NF; ++f) {
        c0[f] = ws[COEF_OFF + f * 5 + 0];
        c1[f] = ws[COEF_OFF + f * 5 + 1];
        c2[f] = ws[COEF_OFF + f * 5 + 2];
        A1[f] = ws[COEF_OFF + f * 5 + 3];
        A2[f] = ws[COEF_OFF + f * 5 + 4];
    }
    __syncthreads();

    // LDS -> regs once; keep for both passes
    float4 xr[CPT / 4];
#pragma unroll
    for (int i = 0; i < CPT / 4; ++i) xr[i] = lds4[swz(t * (CPT / 4) + i)];

    // zero-state pass over own 36-sample chunk
    float s[8];
#pragma unroll
    for (int r = 0; r < 8; ++r) s[r] = 0.f;
#pragma unroll
    for (int i = 0; i < CPT / 4; ++i) {
        float q[4] = {xr[i].x, xr[i].y, xr[i].z, xr[i].w};
#pragma unroll
        for (int e = 0; e < 4; ++e) { float u = q[e]; step1(u, s, c0, c1, c2, A1, A2); }
    }

    // intra-wave affine Kogge-Stone over 64 chunks (registers + shfl)
    float v8[8];
#pragma unroll
    for (int r = 0; r < 8; ++r) v8[r] = s[r];
#pragma unroll
    for (int j = 0; j < 6; ++j) {
        const int st = 1 << j;
        float p[8];
#pragma unroll
        for (int r = 0; r < 8; ++r) p[r] = __shfl_up(v8[r], st, 64);
        if (lane >= st) matvec_acc_sp(v8, mats + j * 64, p);
    }

    // wave aggregates -> LDS
    if (lane == 63) {
#pragma unroll
        for (int r = 0; r < 8; ++r) ldsf[WAGG_L + w * 8 + r] = v8[r];
    }
    __syncthreads();

    // cross-wave prefix, oldest-first Horner with XW1 = A^2304:
    //   s_enter(w) = XW1*s_enter(w-1) + W_{w-1}
    if (w == 0 && lane < 8) {
        float acc[8];
#pragma unroll
        for (int r = 0; r < 8; ++r) acc[r] = 0.f;
        for (int m = 0; m < lane; ++m) {
            matvec_rep_sp(acc, xw1);
#pragma unroll
            for (int r = 0; r < 8; ++r) acc[r] += ldsf[WAGG_L + m * 8 + r];
        }
#pragma unroll
        for (int r = 0; r < 8; ++r) ldsf[PA_L + lane * 8 + r] = acc[r];
    }
    __syncthreads();

    // entry(t) = A^(36*lane) * H_w + v8_{lane-1}
    float H[8];
#pragma unroll
    for (int r = 0; r < 8; ++r) H[r] = ldsf[PA_L + w * 8 + r];
#pragma unroll
    for (int j = 0; j < 6; ++j) {
        if (lane & (1 << j)) matvec_rep_sp(H, mats + j * 64);
    }
    float pv[8];
#pragma unroll
    for (int r = 0; r < 8; ++r) pv[r] = __shfl_up(v8[r], 1, 64);
#pragma unroll
    for (int r = 0; r < 8; ++r) s[r] = H[r] + ((lane > 0) ? pv[r] : 0.f);

    // final pass from exact entry state (x from regs); y -> own LDS slots
#pragma unroll
    for (int i = 0; i < CPT / 4; ++i) {
        float q[4] = {xr[i].x, xr[i].y, xr[i].z, xr[i].w};
#pragma unroll
        for (int e = 0; e < 4; ++e) { float u = q[e]; step1(u, s, c0, c1, c2, A1, A2); q[e] = u; }
        lds4[swz(t * (CPT / 4) + i)] = make_float4(q[0], q[1], q[2], q[3]);
    }
    __syncthreads();

    // coalesced write of the output region (slots >= WSLOT)
    float4* yg4 = (float4*)y;
    const long obase = (long)row * (Ln / 4) + (long)tpos * OSLOT;
#pragma unroll
    for (int j = 0; j < OSLOT / TPB; ++j) {  // 8
        const int n = WSLOT + j * TPB + t;
        yg4[obase + (n - WSLOT)] = lds4[swz(n)];
    }
}

// ---------------------------------------------------------------------------
extern "C" void kernel_launch(void* const* d_in, const int* in_sizes, int n_in,
                              void* d_out, int out_size, void* d_ws, size_t ws_size,
                              hipStream_t stream) {
    const float* x  = (const float*)d_in[0];
    const float* lr = (const float*)d_in[1];
    const float* ra = (const float*)d_in[2];
    const float* b0 = (const float*)d_in[3];
    const float* b1 = (const float*)d_in[4];
    const float* b2 = (const float*)d_in[5];
    float* y  = (float*)d_out;
    float* ws = (float*)d_ws;

    precompute_k<<<dim3(1), dim3(64), 0, stream>>>(lr, ra, b0, b1, b2, ws);
    biquad_k<<<dim3(NT), dim3(TPB), 0, stream>>>(x, ws, y);
}